// Round 3
// baseline (398.040 us; speedup 1.0000x reference)
//
#include <hip/hip_runtime.h>

#define BB 16
#define CC 32
#define HH 256
#define WW 256

#define TWV 30    // valid conv2 output cols per block (conv1 computed on 32)
#define TH 8      // rows per iteration (4 waves x 2 rows)
#define NT 4      // conv2 iterations per block (conv1 does NT+1)
#define CIP 36    // padded ci stride: 72 B -> 2-way LDS banks (free), 8B-aligned

typedef short bf16x8 __attribute__((ext_vector_type(8)));
typedef float f32x16 __attribute__((ext_vector_type(16)));

struct alignas(8)  U2 { unsigned x, y; };
struct alignas(16) U4 { U2 lo, hi; };

__device__ __forceinline__ unsigned short f2bf(float f) {
    unsigned u = __float_as_uint(f);
    u += 0x7fffu + ((u >> 16) & 1u);   // RNE
    return (unsigned short)(u >> 16);
}

// HW packed f32->bf16 (RNE).
__device__ __forceinline__ unsigned cvtpk(float lo, float hi) {
    unsigned r;
    asm("v_cvt_pk_bf16_f32 %0, %1, %2" : "=v"(r) : "v"(lo), "v"(hi));
    return r;
}

// Pre-swizzle weights into per-lane MFMA A-fragment order, bf16:
// wq[layer][st(18)][half(2)][n=co(32)][j(8)], value = w[co][ci][pos]
// with pos = st>>1 (kh*3+kw), ci = (st&1)*16 + half*8 + j.
__global__ void wprep(const float* __restrict__ w1, const float* __restrict__ w2,
                      unsigned short* __restrict__ wq) {
    int idx = blockIdx.x * 256 + threadIdx.x;   // 0..9215
    if (idx >= 18 * 2 * 32 * 8) return;
    int j    = idx & 7;
    int n    = (idx >> 3) & 31;
    int half = (idx >> 8) & 1;
    int st   = idx >> 9;
    int s = st & 1, pos = st >> 1;
    int ci = s * 16 + half * 8 + j;
    int src = (n * CC + ci) * 9 + pos;
    wq[idx]        = f2bf(w1[src]);
    wq[9216 + idx] = f2bf(w2[src]);
}

// Fully fused: conv1 (bias1*gate, relu) -> LDS ring -> conv2 (bias2*gate, relu) + resid.
__global__ __launch_bounds__(256, 2)
void conv_fused(const float* __restrict__ x,
                const unsigned short* __restrict__ wq,   // layer1 table; layer2 at +9216 ushorts
                const float* __restrict__ b1v,
                const float* __restrict__ b2v,
                const float* __restrict__ gate,
                float* __restrict__ out)
{
    __shared__ unsigned short xs[TH + 2][34][CIP];      // 10*34*36*2 = 24480 B
    __shared__ unsigned short hs[2][TH][34][CIP];       // 2*8*34*36*2 = 39168 B (cols 32,33 pad)
    __shared__ float gs[CC], bs1[CC], bs2[CC];

    const int t     = threadIdx.x;
    const int b     = blockIdx.z;
    const int x0    = blockIdx.x * TWV;
    const int ybase = blockIdx.y * (TH * NT);

    if (t < CC) {
        float gv = gate[b * CC + t];
        gs[t]  = gv > 0.f ? gv : 0.f;
        bs1[t] = b1v[t];
        bs2[t] = b2v[t];
    }

    const int lane = t & 63;
    const int wv   = t >> 6;       // wave 0..3
    const int col  = lane & 31;    // MFMA n (pixel/col) and A m (co) lane index
    const int half = lane >> 5;
    const int r0 = wv * 2, r1 = r0 + 1;

    // Both layers' weight fragments resident (36 x 4 VGPR). L2-hot 36KB table.
    // NOTE: U4 = 8 ushorts, so layer-2 base is wq + 9216 (ushorts) = U4 index 1152.
    bf16x8 wf1[18], wf2[18];
    const U4* wq1 = (const U4*)wq;
    const U4* wq2 = (const U4*)(wq + 9216);
    #pragma unroll
    for (int st = 0; st < 18; ++st) {
        wf1[st] = __builtin_bit_cast(bf16x8, wq1[(st * 2 + half) * 32 + col]);
        wf2[st] = __builtin_bit_cast(bf16x8, wq2[(st * 2 + half) * 32 + col]);
    }

    // Pixel-per-thread staging decomposition (340 = 10x34 pixels; 84 threads own 2).
    const int yA = t / 34,        xA = t - yA * 34;
    const int pB = 256 + t;
    const int yB = pB / 34,       xB = pB - yB * 34;
    const bool hasB = t < 84;
    const float* xb = x + (size_t)b * CC * HH * WW;

    // Stage x rows [rowT, rowT+9] x cols [x0-2, x0+31] into xs, bf16 channels-last.
    auto stage = [&](int rowT) {
        float va[32], vb[32];
        #pragma unroll
        for (int j = 0; j < 32; ++j) { va[j] = 0.f; vb[j] = 0.f; }
        const int gyA = rowT + yA, gxA = x0 - 2 + xA;
        if (gyA >= 0 && gyA < HH && gxA >= 0 && gxA < WW) {
            const float* pa = xb + (gyA * WW + gxA);
            #pragma unroll
            for (int j = 0; j < 32; ++j) va[j] = pa[j * (HH * WW)];
        }
        const int gyB = rowT + yB, gxB = x0 - 2 + xB;
        if (hasB && gyB >= 0 && gyB < HH && gxB >= 0 && gxB < WW) {
            const float* pb = xb + (gyB * WW + gxB);
            #pragma unroll
            for (int j = 0; j < 32; ++j) vb[j] = pb[j * (HH * WW)];
        }
        #pragma unroll
        for (int k = 0; k < 8; ++k) {
            U2 w; w.x = cvtpk(va[4 * k + 0], va[4 * k + 1]);
                  w.y = cvtpk(va[4 * k + 2], va[4 * k + 3]);
            *(U2*)&xs[yA][xA][4 * k] = w;
        }
        if (hasB) {
            #pragma unroll
            for (int k = 0; k < 8; ++k) {
                U2 w; w.x = cvtpk(vb[4 * k + 0], vb[4 * k + 1]);
                      w.y = cvtpk(vb[4 * k + 2], vb[4 * k + 3]);
                *(U2*)&xs[yB][xB][4 * k] = w;
            }
        }
    };

    // conv1 iteration i: rows gR = ybase-1+8i+r (r=0..7), cols gC = x0-1+c (c=0..31).
    // Output -> hs[i&1], zero-masked outside the image (conv2 SAME padding).
    auto conv1_iter = [&](int i) {
        f32x16 acc0 = {0,0,0,0,0,0,0,0,0,0,0,0,0,0,0,0};
        f32x16 acc1 = {0,0,0,0,0,0,0,0,0,0,0,0,0,0,0,0};
        const unsigned short* xsb0 = &xs[r0][col][half * 8];
        const unsigned short* xsb1 = &xs[r1][col][half * 8];
        #pragma unroll
        for (int st = 0; st < 18; ++st) {
            const int pos = st >> 1, s = st & 1;
            const int kh = pos / 3, kw = pos - kh * 3;
            const int off = (kh * 34 + kw) * CIP + s * 16;
            U4 xa, xv;
            xa.lo = *(const U2*)(xsb0 + off);
            xa.hi = *(const U2*)(xsb0 + off + 4);
            xv.lo = *(const U2*)(xsb1 + off);
            xv.hi = *(const U2*)(xsb1 + off + 4);
            acc0 = __builtin_amdgcn_mfma_f32_32x32x16_bf16(wf1[st], __builtin_bit_cast(bf16x8, xa), acc0, 0, 0, 0);
            acc1 = __builtin_amdgcn_mfma_f32_32x32x16_bf16(wf1[st], __builtin_bit_cast(bf16x8, xv), acc1, 0, 0, 0);
        }
        const int rowbase = ybase - 1 + 8 * i;
        const int gR0 = rowbase + r0, gR1 = rowbase + r1;
        const int gC  = x0 - 1 + col;
        const bool okC = (unsigned)gC < (unsigned)WW;
        const bool ok0 = okC && ((unsigned)gR0 < (unsigned)HH);
        const bool ok1 = okC && ((unsigned)gR1 < (unsigned)HH);
        unsigned short* h0 = &hs[i & 1][r0][col][0];
        unsigned short* h1 = &hs[i & 1][r1][col][0];
        #pragma unroll
        for (int g = 0; g < 4; ++g) {
            int c0 = 8 * g + 4 * half;    // regs 4g..4g+3 -> consecutive co
            float a0 = fmaxf((acc0[4 * g + 0] + bs1[c0 + 0]) * gs[c0 + 0], 0.f);
            float a1 = fmaxf((acc0[4 * g + 1] + bs1[c0 + 1]) * gs[c0 + 1], 0.f);
            float a2 = fmaxf((acc0[4 * g + 2] + bs1[c0 + 2]) * gs[c0 + 2], 0.f);
            float a3 = fmaxf((acc0[4 * g + 3] + bs1[c0 + 3]) * gs[c0 + 3], 0.f);
            if (!ok0) { a0 = 0.f; a1 = 0.f; a2 = 0.f; a3 = 0.f; }
            U2 w0; w0.x = cvtpk(a0, a1); w0.y = cvtpk(a2, a3);
            *(U2*)(h0 + c0) = w0;
            float d0 = fmaxf((acc1[4 * g + 0] + bs1[c0 + 0]) * gs[c0 + 0], 0.f);
            float d1 = fmaxf((acc1[4 * g + 1] + bs1[c0 + 1]) * gs[c0 + 1], 0.f);
            float d2 = fmaxf((acc1[4 * g + 2] + bs1[c0 + 2]) * gs[c0 + 2], 0.f);
            float d3 = fmaxf((acc1[4 * g + 3] + bs1[c0 + 3]) * gs[c0 + 3], 0.f);
            if (!ok1) { d0 = 0.f; d1 = 0.f; d2 = 0.f; d3 = 0.f; }
            U2 w1; w1.x = cvtpk(d0, d1); w1.y = cvtpk(d2, d3);
            *(U2*)(h1 + c0) = w1;
        }
    };

    // conv2 iteration j: output rows gO = ybase+8j+r, cols gX = x0+n (n<30 valid).
    // Input row gO-1+kh lives in hs bank (j+(q>>3))&1, slot q&7, q = r+kh.
    auto conv2_iter = [&](int j) {
        f32x16 acc0 = {0,0,0,0,0,0,0,0,0,0,0,0,0,0,0,0};
        f32x16 acc1 = {0,0,0,0,0,0,0,0,0,0,0,0,0,0,0,0};
        const unsigned short* hb0 = &hs[j & 1][0][0][0];
        const unsigned short* hb1 = &hs[(j + 1) & 1][0][0][0];
        if (wv < 3) {
            // q = r+kh <= 7: everything in bank j&1, constant offsets.
            const unsigned short* p0 = hb0 + (r0 * 34 + col) * CIP + half * 8;
            const unsigned short* p1 = hb0 + (r1 * 34 + col) * CIP + half * 8;
            #pragma unroll
            for (int st = 0; st < 18; ++st) {
                const int pos = st >> 1, s = st & 1;
                const int kh = pos / 3, kw = pos - kh * 3;
                const int off = (kh * 34 + kw) * CIP + s * 16;
                U4 xa, xv;
                xa.lo = *(const U2*)(p0 + off);
                xa.hi = *(const U2*)(p0 + off + 4);
                xv.lo = *(const U2*)(p1 + off);
                xv.hi = *(const U2*)(p1 + off + 4);
                acc0 = __builtin_amdgcn_mfma_f32_32x32x16_bf16(wf2[st], __builtin_bit_cast(bf16x8, xa), acc0, 0, 0, 0);
                acc1 = __builtin_amdgcn_mfma_f32_32x32x16_bf16(wf2[st], __builtin_bit_cast(bf16x8, xv), acc1, 0, 0, 0);
            }
        } else {
            // wv==3: r0=6, r1=7 -> q0 = 6+kh in {6,7,8}, q1 = 7+kh in {7,8,9}; bank split compile-time.
            const unsigned short* c0p = hb0 + col * CIP + half * 8;
            const unsigned short* c1p = hb1 + col * CIP + half * 8;
            #pragma unroll
            for (int st = 0; st < 18; ++st) {
                const int pos = st >> 1, s = st & 1;
                const int kh = pos / 3, kw = pos - kh * 3;
                const int q0 = 6 + kh, q1 = 7 + kh;
                const unsigned short* p0 = (q0 >= 8 ? c1p : c0p) + ((q0 & 7) * 34 + kw) * CIP + s * 16;
                const unsigned short* p1 = (q1 >= 8 ? c1p : c0p) + ((q1 & 7) * 34 + kw) * CIP + s * 16;
                U4 xa, xv;
                xa.lo = *(const U2*)(p0);
                xa.hi = *(const U2*)(p0 + 4);
                xv.lo = *(const U2*)(p1);
                xv.hi = *(const U2*)(p1 + 4);
                acc0 = __builtin_amdgcn_mfma_f32_32x32x16_bf16(wf2[st], __builtin_bit_cast(bf16x8, xa), acc0, 0, 0, 0);
                acc1 = __builtin_amdgcn_mfma_f32_32x32x16_bf16(wf2[st], __builtin_bit_cast(bf16x8, xv), acc1, 0, 0, 0);
            }
        }
        const int gO0 = ybase + 8 * j + r0;
        const int gO1 = gO0 + 1;
        const int gX  = x0 + col;
        const bool okN = (col < TWV) && (gX < WW);
        float* ob = out + (size_t)b * CC * HH * WW;
        const float* rb = x + (size_t)b * CC * HH * WW;
        if (okN) {
            #pragma unroll
            for (int reg = 0; reg < 16; ++reg) {
                int co = (reg & 3) + 8 * (reg >> 2) + 4 * half;
                int i0 = (co * HH + gO0) * WW + gX;
                int i1 = (co * HH + gO1) * WW + gX;
                float v0 = (acc0[reg] + bs2[co]) * gs[co];
                float v1 = (acc1[reg] + bs2[co]) * gs[co];
                ob[i0] = fmaxf(v0, 0.f) + rb[i0];
                ob[i1] = fmaxf(v1, 0.f) + rb[i1];
            }
        }
    };

    // ---- schedule: conv1 runs one 8-row iteration ahead of conv2 ----
    stage(ybase - 2);
    __syncthreads();
    conv1_iter(0);
    #pragma unroll 1
    for (int i = 1; i <= NT; ++i) {
        __syncthreads();                 // B1: conv1(i-1) xs reads done; conv2(i-2) hs reads done
        stage(ybase - 2 + 8 * i);        // overwrite xs
        __syncthreads();                 // B2: xs(i) ready
        conv1_iter(i);                   // -> hs[i&1]
        __syncthreads();                 // B3: hs[i&1] visible
        conv2_iter(i - 1);               // reads hs[(i-1)&1] + hs[i&1] rows 0..1
    }
}

extern "C" void kernel_launch(void* const* d_in, const int* in_sizes, int n_in,
                              void* d_out, int out_size, void* d_ws, size_t ws_size,
                              hipStream_t stream) {
    const float* x  = (const float*)d_in[0];
    const float* gv = (const float*)d_in[1];
    const float* w1 = (const float*)d_in[2];
    const float* b1 = (const float*)d_in[3];
    const float* w2 = (const float*)d_in[4];
    const float* b2 = (const float*)d_in[5];
    float* out = (float*)d_out;

    unsigned short* wq = (unsigned short*)d_ws;   // 2 x 9216 bf16 frag tables

    wprep<<<36, 256, 0, stream>>>(w1, w2, wq);

    dim3 grid((WW + TWV - 1) / TWV, HH / (TH * NT), BB);  // (9, 8, 16) = 1152 blocks
    conv_fused<<<grid, 256, 0, stream>>>(x, wq, b1, b2, gv, out);
}